// Round 6
// baseline (190.763 us; speedup 1.0000x reference)
//
#include <hip/hip_runtime.h>
#include <math.h>

#define DD 1024
#define HH1 4096
#define HH2 4096

typedef __attribute__((ext_vector_type(4))) float f32x4;
typedef unsigned short ushort_t;

// fast-path ws layout:
//   f32 idx [0)      dotacc (4096)   raw layer-1 dot partials (atomicAdd)
//           [4096)   sqacc  (4096)   raw sum-of-squares partials
//           [8192)   cv     (4096)
//           [12288)  cd     (4096)
//           [16384)  P      (512)    per-block GEMM partials
//   byte    [67584)  counter (u32)   k4 last-block flag
//   byte    [131072) A'' = e4m3(W2 .* s .* 64)  4096x4096 B, pair-permuted k
//   byte    [16908288) B'' = e4m3(W1^T .* 32)   1024x4096 B, pair-permuted k
//   total 21,102,592 B  (proven ws >= 42 MB in R3-R5)
#define WS_FAST_BYTES 21102592ull

__device__ inline void wave_reduce2(float& a, float& b) {
  #pragma unroll
  for (int off = 32; off > 0; off >>= 1) {
    a += __shfl_down(a, off, 64);
    b += __shfl_down(b, off, 64);
  }
}

// ---- fp32 -> OCP e4m3fn ----
#if __has_builtin(__builtin_amdgcn_cvt_pk_fp8_f32)
__device__ inline unsigned int cvt4_e4m3(float a, float b, float c, float d) {
  unsigned int v = 0;
  v = __builtin_amdgcn_cvt_pk_fp8_f32(a, b, v, false);
  v = __builtin_amdgcn_cvt_pk_fp8_f32(c, d, v, true);
  return v;
}
#else
__device__ inline unsigned int f2fp8(float f) {  // manual RNE e4m3fn
  union { float f; unsigned int u; } v; v.f = f;
  unsigned int s = (v.u >> 24) & 0x80u;
  int e = (int)((v.u >> 23) & 0xff) - 127;
  if (e >= 9) return s | 0x7e;
  if (e >= -6) {
    unsigned int q = (v.u >> 20) & 7u;
    unsigned int rest = v.u & 0xfffffu;
    unsigned int r = (rest > 0x80000u) || ((rest == 0x80000u) && (q & 1u));
    unsigned int mag = (((unsigned int)(e + 7) << 3) | q) + r;
    if (mag > 0x7e) mag = 0x7e;
    return s | mag;
  }
  float sc = fabsf(f) * 512.f;
  unsigned int q = (unsigned int)(sc + 0.5f);
  if (q > 8u) q = 8u;
  return s | q;
}
__device__ inline unsigned int cvt4_e4m3(float a, float b, float c, float d) {
  return f2fp8(a) | (f2fp8(b) << 8) | (f2fp8(c) << 16) | (f2fp8(d) << 24);
}
#endif

// async global->LDS, 16 B/lane; lds dst = wave-uniform base + lane*16
__device__ inline void gl_lds16(const void* g, void* l) {
  __builtin_amdgcn_global_load_lds(
      (const __attribute__((address_space(1))) unsigned int*)g,
      (__attribute__((address_space(3))) unsigned int*)l, 16, 0, 0);
}

// pair-permuted u32 index within a 1024-u32 (4096-k) row:
// 64-k blocks in order; within each, 8-byte chunks stored as pairs
// [c,c+4] c=0..3  -> u32 position = blk*16 + (c&3)*4 + (c>>2)*2 + half
__device__ inline int perm_u32_idx(int j) {  // j = u32 index 0..1023 (k/4)
  int c = (j >> 1) & 7;
  return (j >> 4) * 16 + (c & 3) * 4 + (c >> 2) * 2 + (j & 1);
}

// kA: grid 256 = 64 h-blocks x 4 i-blocks. Partial layer-1 dots (atomicAdd to
// raw accumulators) + transpose-convert B''[i][h] = e4m3(32*W1[h][i]), paired.
__global__ __launch_bounds__(256) void kA_l1t(
    const float* __restrict__ W1, const float* __restrict__ x,
    unsigned char* __restrict__ Bp8, float* __restrict__ dotacc,
    float* __restrict__ sqacc) {
  __shared__ unsigned int T2[64][65];  // [i-chunk][h-row], stride 65 -> conflict-free
  const int tid = threadIdx.x, lane = tid & 63, w = tid >> 6;
  const int hb = blockIdx.x >> 2, ib = blockIdx.x & 3;
  const int h0 = hb * 64, i0 = ib * 256;
  const float4 xv = ((const float4*)x)[i0 / 4 + lane];
  #pragma unroll
  for (int rr = 0; rr < 16; ++rr) {
    int r = w * 16 + rr;  // 0..63
    float4 wv = *(const float4*)(W1 + (size_t)(h0 + r) * DD + i0 + lane * 4);
    float dot = wv.x * xv.x + wv.y * xv.y + wv.z * xv.z + wv.w * xv.w;
    float sq = wv.x * wv.x + wv.y * wv.y + wv.z * wv.z + wv.w * wv.w;
    T2[lane][r] = cvt4_e4m3(wv.x * 32.f, wv.y * 32.f, wv.z * 32.f, wv.w * 32.f);
    wave_reduce2(dot, sq);
    if (lane == 0) {
      atomicAdd(&dotacc[h0 + r], dot);
      atomicAdd(&sqacc[h0 + r], sq);
    }
  }
  __syncthreads();
  #pragma unroll
  for (int pi = 0; pi < 4; ++pi) {
    int li = pi * 64 + (tid >> 2);     // local i 0..255
    int c = tid & 3;                   // 16-B phys chunk
    int ic = li >> 2;
    int bl = (li & 3) * 8;
    const unsigned int* tp = &T2[ic][0];
    unsigned int o[4];
    #pragma unroll
    for (int j = 0; j < 4; ++j) {
      int rb = 8 * c + (j & 1) * 4 + (j >> 1) * 32;  // h-base of this u32
      unsigned int b0 = (tp[rb + 0] >> bl) & 0xffu;
      unsigned int b1 = (tp[rb + 1] >> bl) & 0xffu;
      unsigned int b2 = (tp[rb + 2] >> bl) & 0xffu;
      unsigned int b3 = (tp[rb + 3] >> bl) & 0xffu;
      o[j] = b0 | (b1 << 8) | (b2 << 16) | (b3 << 24);
    }
    uint4 ov = make_uint4(o[0], o[1], o[2], o[3]);
    *(uint4*)(Bp8 + (size_t)(i0 + li) * HH1 + h0 + c * 16) = ov;
  }
}

// k0a: per-row g of W2. Preamble: derive u0/q from raw accumulators (fast tanh)
// into LDS. Then z=W2[g]·u0+b2, d=W2[g]·q, A''[g]=e4m3(64*W2[g].*s) paired;
// cv[g]=c*v0, cd[g]=c*d.
__global__ __launch_bounds__(256) void k0a_layer2conv(
    const float* __restrict__ W2, const float* __restrict__ b1,
    const float* __restrict__ b2, const float* __restrict__ W3,
    const float* __restrict__ dotacc, const float* __restrict__ sqacc,
    unsigned char* __restrict__ Ap8, float* __restrict__ cv,
    float* __restrict__ cd) {
  __shared__ __align__(16) float uu[HH1];
  __shared__ __align__(16) float qq[HH1];
  __shared__ float lds[8];
  const int g = blockIdx.x;
  const int tid = threadIdx.x;
  for (int h = tid; h < HH1; h += 256) {
    float dt = dotacc[h] + b1[h];
    float e = __expf(2.f * dt);
    float u = 1.f - 2.f / (e + 1.f);  // tanh(dt)
    float s = 1.f - u * u;
    uu[h] = u;
    qq[h] = -2.f * u * s * sqacc[h];
  }
  __syncthreads();
  const float4* row = (const float4*)(W2 + (size_t)g * HH1);
  const f32x4* u4 = (const f32x4*)uu;
  const f32x4* q4 = (const f32x4*)qq;
  unsigned int* arow = (unsigned int*)Ap8 + (size_t)g * 1024;
  float zacc = 0.f, dacc = 0.f;
  #pragma unroll
  for (int it = 0; it < 4; ++it) {
    int j = tid + it * 256;  // u32 index 0..1023
    float4 w = row[j];
    f32x4 u = u4[j];
    f32x4 qv = q4[j];
    float sx = 1.f - u[0] * u[0], sy = 1.f - u[1] * u[1];
    float sz = 1.f - u[2] * u[2], sw = 1.f - u[3] * u[3];
    zacc += w.x * u[0] + w.y * u[1] + w.z * u[2] + w.w * u[3];
    dacc += w.x * qv[0] + w.y * qv[1] + w.z * qv[2] + w.w * qv[3];
    arow[perm_u32_idx(j)] =
        cvt4_e4m3(w.x * sx * 64.f, w.y * sy * 64.f, w.z * sz * 64.f, w.w * sw * 64.f);
  }
  wave_reduce2(zacc, dacc);
  int lane = tid & 63, wid = tid >> 6;
  if (lane == 0) { lds[wid * 2] = zacc; lds[wid * 2 + 1] = dacc; }
  __syncthreads();
  if (tid == 0) {
    float z = lds[0] + lds[2] + lds[4] + lds[6] + b2[g];
    float d = lds[1] + lds[3] + lds[5] + lds[7];
    float e = __expf(2.f * z);
    float v = 1.f - 2.f / (e + 1.f);
    float t = 1.f - v * v;
    float c = W3[g] * t;
    cv[g] = c * v;
    cd[g] = c * d;
  }
}

// k4: fp8 GEMM-BT M'' = A''·B''^T, tile 128(g) x 64(i), BK=128 (32 iters).
// LDS rows 128 B = 8 pair-slots of 16 B; slot q holds logical pair q^(row&7).
// One b128 frag read = two MFMA operands (kk even in lo 8B, kk odd in hi 8B).
// Epilogue: P[block] = 2^-22 * Σ cv[g]*M''[g,i]^2; last block: out = Σcd - 2ΣP.
__global__ __launch_bounds__(256) void k4_fp8(
    const unsigned char* __restrict__ Ap8, const unsigned char* __restrict__ Bp8,
    const float* __restrict__ cv, const float* __restrict__ cd,
    float* __restrict__ P, unsigned int* __restrict__ cnt,
    float* __restrict__ out) {
  __shared__ __align__(16) unsigned char As8[128][128];
  __shared__ __align__(16) unsigned char Bs8[64][128];
  __shared__ float red[4];
  __shared__ float fin[5];
  const int tid = threadIdx.x;
  const int lane = tid & 63;
  const int wave = tid >> 6;
  const int wm = wave >> 1, wn = wave & 1;
  const int l = blockIdx.x;
  const int xcd = l & 7, j = l >> 3;
  const int g0 = (xcd * 4 + (j & 3)) * 128;
  const int i0 = (j >> 2) * 64;

  f32x4 acc[4][2];
  const f32x4 zero = {0.f, 0.f, 0.f, 0.f};
  #pragma unroll
  for (int mt = 0; mt < 4; ++mt)
    #pragma unroll
    for (int nt = 0; nt < 2; ++nt) acc[mt][nt] = zero;

  const int fr = lane & 15;
  const int fc = lane >> 4;
  const int srow = lane >> 3;  // staging: 8 rows/call
  const int schk = lane & 7;   // staging: phys 16B slot

  for (int ko = 0; ko < 32; ++ko) {
    const int kb = ko * 128;  // byte offset in row
    #pragma unroll
    for (int p = 0; p < 4; ++p) {
      int row = wave * 32 + p * 8 + srow;
      int q = schk ^ (row & 7);
      gl_lds16(Ap8 + (size_t)(g0 + row) * HH1 + kb + q * 16,
               (char*)&As8[0][0] + (wave * 32 + p * 8) * 128 + lane * 16);
    }
    #pragma unroll
    for (int p = 0; p < 2; ++p) {
      int row = wave * 16 + p * 8 + srow;
      int q = schk ^ (row & 7);
      gl_lds16(Bp8 + (size_t)(i0 + row) * HH1 + kb + q * 16,
               (char*)&Bs8[0][0] + (wave * 16 + p * 8) * 128 + lane * 16);
    }
    __syncthreads();
    union U4 { uint4 v; long ll[2]; };
    U4 a4[4][2], b4[2][2];
    #pragma unroll
    for (int mt = 0; mt < 4; ++mt) {
      int row = wm * 64 + mt * 16 + fr;
      #pragma unroll
      for (int pg = 0; pg < 2; ++pg) {
        int q = (pg * 4 + fc) ^ (row & 7);
        a4[mt][pg].v = *(const uint4*)&As8[row][q * 16];
      }
    }
    #pragma unroll
    for (int nt = 0; nt < 2; ++nt) {
      int row = wn * 32 + nt * 16 + fr;
      #pragma unroll
      for (int pg = 0; pg < 2; ++pg) {
        int q = (pg * 4 + fc) ^ (row & 7);
        b4[nt][pg].v = *(const uint4*)&Bs8[row][q * 16];
      }
    }
    #pragma unroll
    for (int pg = 0; pg < 2; ++pg)
      #pragma unroll
      for (int hf = 0; hf < 2; ++hf)
        #pragma unroll
        for (int mt = 0; mt < 4; ++mt)
          #pragma unroll
          for (int nt = 0; nt < 2; ++nt)
            acc[mt][nt] = __builtin_amdgcn_mfma_f32_16x16x32_fp8_fp8(
                a4[mt][pg].ll[hf], b4[nt][pg].ll[hf], acc[mt][nt], 0, 0, 0);
    __syncthreads();
  }

  float part = 0.f;
  #pragma unroll
  for (int mt = 0; mt < 4; ++mt) {
    #pragma unroll
    for (int r = 0; r < 4; ++r) {
      int g = g0 + wm * 64 + mt * 16 + fc * 4 + r;
      float c = cv[g];
      float ss = 0.f;
      #pragma unroll
      for (int nt = 0; nt < 2; ++nt) {
        float v = acc[mt][nt][r];
        ss += v * v;
      }
      part += c * ss;
    }
  }
  #pragma unroll
  for (int off = 32; off > 0; off >>= 1) part += __shfl_down(part, off, 64);
  if (lane == 0) red[wave] = part;
  __syncthreads();
  if (tid == 0) {
    P[l] = (red[0] + red[1] + red[2] + red[3]) * 2.384185791015625e-07f; // 2^-22
    __threadfence();
    unsigned int old = atomicAdd(cnt, 1u);
    fin[4] = (old == 511u) ? 1.f : 0.f;
  }
  __syncthreads();
  if (fin[4] != 0.f) {
    __threadfence();  // acquire all P stores
    float a = 0.f, b = 0.f;
    for (int jj = tid; jj < HH2; jj += 256) a += cd[jj];
    for (int jj = tid; jj < 512; jj += 256) b += P[jj];
    float v = a - 2.f * b;
    #pragma unroll
    for (int off = 32; off > 0; off >>= 1) v += __shfl_down(v, off, 64);
    int ln = tid & 63, wd = tid >> 6;
    if (ln == 0) fin[wd] = v;
    __syncthreads();
    if (tid == 0) out[0] = fin[0] + fin[1] + fin[2] + fin[3];
  }
}

// ---------------- fallback (fp32, tiny ws; R1-proven) ----------------

__global__ __launch_bounds__(256) void k1_slow(
    const float* __restrict__ W1, const float* __restrict__ x,
    const float* __restrict__ b1, float* __restrict__ u0,
    float* __restrict__ q, float* __restrict__ s_out,
    float* __restrict__ out) {
  int h = blockIdx.x;
  int tid = threadIdx.x;
  const float4* row = (const float4*)(W1 + (size_t)h * DD);
  const float4* x4 = (const float4*)x;
  float4 w = row[tid];
  float4 xv = x4[tid];
  float dot = w.x * xv.x + w.y * xv.y + w.z * xv.z + w.w * xv.w;
  float sq = w.x * w.x + w.y * w.y + w.z * w.z + w.w * w.w;
  wave_reduce2(dot, sq);
  __shared__ float lds[8];
  int lane = tid & 63, wid = tid >> 6;
  if (lane == 0) { lds[wid * 2] = dot; lds[wid * 2 + 1] = sq; }
  __syncthreads();
  if (tid == 0) {
    float dsum = lds[0] + lds[2] + lds[4] + lds[6];
    float rsum = lds[1] + lds[3] + lds[5] + lds[7];
    float a0 = dsum + b1[h];
    float u = tanhf(a0);
    float s = 1.f - u * u;
    u0[h] = u;
    s_out[h] = s;
    q[h] = -2.f * u * s * rsum;
    if (h == 0) out[0] = 0.f;
  }
}

__global__ __launch_bounds__(256) void k2_slow(
    const float* __restrict__ W2, const float* __restrict__ b2,
    const float* __restrict__ W3, const float* __restrict__ u0,
    const float* __restrict__ q, float* __restrict__ cv,
    float* __restrict__ out) {
  int g = blockIdx.x;
  int tid = threadIdx.x;
  const float4* row = (const float4*)(W2 + (size_t)g * HH1);
  const float4* u4 = (const float4*)u0;
  const float4* q4 = (const float4*)q;
  float zacc = 0.f, dacc = 0.f;
  for (int j = tid; j < HH1 / 4; j += 256) {
    float4 w = row[j];
    float4 u = u4[j];
    float4 qq = q4[j];
    zacc += w.x * u.x + w.y * u.y + w.z * u.z + w.w * u.w;
    dacc += w.x * qq.x + w.y * qq.y + w.z * qq.z + w.w * qq.w;
  }
  wave_reduce2(zacc, dacc);
  __shared__ float lds[8];
  int lane = tid & 63, wid = tid >> 6;
  if (lane == 0) { lds[wid * 2] = zacc; lds[wid * 2 + 1] = dacc; }
  __syncthreads();
  if (tid == 0) {
    float z = lds[0] + lds[2] + lds[4] + lds[6] + b2[g];
    float d = lds[1] + lds[3] + lds[5] + lds[7];
    float v = tanhf(z);
    float t = 1.f - v * v;
    float c = W3[g] * t;
    cv[g] = c * v;
    atomicAdd(out, c * d);
  }
}

__global__ __launch_bounds__(256) void k4_slow(
    const float* __restrict__ W2, const float* __restrict__ W1,
    const float* __restrict__ s, const float* __restrict__ cv,
    float* __restrict__ out) {
  __shared__ float As[32][68];
  __shared__ float Bs[32][68];
  int tid = threadIdx.x;
  int g0 = blockIdx.y * 64;
  int i0 = blockIdx.x * 64;
  int tr = (tid / 16) * 4;
  int tc = (tid % 16) * 4;
  float acc[4][4] = {};
  for (int k0 = 0; k0 < HH1; k0 += 32) {
    for (int ll = tid; ll < (64 * 32 / 4); ll += 256) {
      int row = ll / 8;
      int c4 = ll % 8;
      float4 w = *(const float4*)(W2 + (size_t)(g0 + row) * HH1 + k0 + c4 * 4);
      float4 sv = *(const float4*)(s + k0 + c4 * 4);
      As[c4 * 4 + 0][row] = w.x * sv.x;
      As[c4 * 4 + 1][row] = w.y * sv.y;
      As[c4 * 4 + 2][row] = w.z * sv.z;
      As[c4 * 4 + 3][row] = w.w * sv.w;
    }
    for (int ll = tid; ll < (32 * 64 / 4); ll += 256) {
      int row = ll / 16;
      int c4 = ll % 16;
      float4 w = *(const float4*)(W1 + (size_t)(k0 + row) * DD + i0 + c4 * 4);
      *(float4*)&Bs[row][c4 * 4] = w;
    }
    __syncthreads();
    #pragma unroll
    for (int k = 0; k < 32; ++k) {
      float4 av = *(const float4*)&As[k][tr];
      float4 bv = *(const float4*)&Bs[k][tc];
      float a_[4] = {av.x, av.y, av.z, av.w};
      float b_[4] = {bv.x, bv.y, bv.z, bv.w};
      #pragma unroll
      for (int r = 0; r < 4; ++r)
        #pragma unroll
        for (int c = 0; c < 4; ++c)
          acc[r][c] += a_[r] * b_[c];
    }
    __syncthreads();
  }
  float contrib = 0.f;
  #pragma unroll
  for (int r = 0; r < 4; ++r) {
    float ss = acc[r][0] * acc[r][0] + acc[r][1] * acc[r][1] +
               acc[r][2] * acc[r][2] + acc[r][3] * acc[r][3];
    contrib += cv[g0 + tr + r] * ss;
  }
  #pragma unroll
  for (int off = 32; off > 0; off >>= 1) contrib += __shfl_down(contrib, off, 64);
  __shared__ float red[4];
  int lane = tid & 63, wid = tid >> 6;
  if (lane == 0) red[wid] = contrib;
  __syncthreads();
  if (tid == 0) atomicAdd(out, -2.f * (red[0] + red[1] + red[2] + red[3]));
}

extern "C" void kernel_launch(void* const* d_in, const int* in_sizes, int n_in,
                              void* d_out, int out_size, void* d_ws, size_t ws_size,
                              hipStream_t stream) {
  const float* x  = (const float*)d_in[0];
  const float* W1 = (const float*)d_in[1];
  const float* b1 = (const float*)d_in[2];
  const float* W2 = (const float*)d_in[3];
  const float* b2 = (const float*)d_in[4];
  const float* W3 = (const float*)d_in[5];
  // b3 (d_in[6]) vanishes under the Laplacian.
  float* out = (float*)d_out;
  float* ws = (float*)d_ws;

  if (ws_size >= WS_FAST_BYTES) {
    float* dotacc = ws;
    float* sqacc  = ws + 4096;
    float* cv     = ws + 8192;
    float* cd     = ws + 12288;
    float* P      = ws + 16384;
    unsigned int* cnt = (unsigned int*)((char*)d_ws + 67584);
    unsigned char* Ap8 = (unsigned char*)d_ws + 131072;
    unsigned char* Bp8 = (unsigned char*)d_ws + 16908288;
    // zero dotacc/sqacc (+ counter region) — ws is re-poisoned before each call
    hipMemsetAsync(d_ws, 0, 69632, stream);
    hipLaunchKernelGGL(kA_l1t, dim3(256), dim3(256), 0, stream,
                       W1, x, Bp8, dotacc, sqacc);
    hipLaunchKernelGGL(k0a_layer2conv, dim3(HH2), dim3(256), 0, stream,
                       W2, b1, b2, W3, dotacc, sqacc, Ap8, cv, cd);
    hipLaunchKernelGGL(k4_fp8, dim3(512), dim3(256), 0, stream,
                       Ap8, Bp8, cv, cd, P, cnt, out);
  } else {
    float* u0 = ws;
    float* q  = ws + 4096;
    float* s  = ws + 8192;
    float* cv = ws + 12288;
    hipLaunchKernelGGL(k1_slow, dim3(HH1), dim3(256), 0, stream,
                       W1, x, b1, u0, q, s, out);
    hipLaunchKernelGGL(k2_slow, dim3(HH2), dim3(256), 0, stream,
                       W2, b2, W3, u0, q, cv, out);
    hipLaunchKernelGGL(k4_slow, dim3(DD / 64, HH2 / 64), dim3(256), 0, stream,
                       W2, W1, s, cv, out);
  }
}